// Round 8
// baseline (199.249 us; speedup 1.0000x reference)
//
#include <hip/hip_runtime.h>
#include <stdint.h>

typedef unsigned int u32;
typedef unsigned long long u64;

#define SCORE_THR 0.05f
#define NMS_THR   0.5f
#define TK        2048
#define CAP       4096
#define BASE14    ((int)(0x3D4CCCCDu >> 14))   // (bits of 0.05f) >> 14 = 62771
#define MAGIC11   3123612579ull                // ceil(2^35/11); exact /11 for e < 2^35
#define NREP      8
#define CHUNK     3
#define NCHUNK    22                           // ceil(64/3)

// ---------------- ws layout (bytes) ----------------
// 0      : offs    u32[4096]  (fully written by k_scan -> NOT memset)
// 16384  : binpos  u32[4096]  (zeroed)
// 32768  : hdr     u32[64]    (zeroed) hdr[3]=pivot bin hdr[5]=n>=pivot hdr[6]=total
// 33024  : cand_bx f32[2048*4] (zeroed: padding slots)
// 65792  : nms_bx  f32[2048*4] (zeroed)
// 98560  : vals    f32[2048]   (zeroed)
// 106752 : maskT   u32[64][2048] (512 KB, COLUMN-major: maskT[colword][row])
//          hrep u32[8][4096] (128 KB) ALIASES maskT[0:128K]  (dead after k_scan)
//          buf  u64[4096]    (32 KB)  ALIASES maskT[128K:160K] (dead before k_mask)
#define WS_OFFS   0
#define WS_BINPOS 16384
#define WS_HDR    32768
#define WS_CBX    33024
#define WS_NBX    65792
#define WS_VALS   98560
#define WS_MASK   106752
#define WS_HREP   106752
#define WS_BUF    237824

// ---- histogram over key bits [30:14]: contiguous chunks, 4-wide float4 MLP,
//      LDS hist, merge into 8 replicated global hists (contention /8) ----
__global__ void k_hist(const float* __restrict__ scores,
                       const float* __restrict__ center,
                       int R, u32* __restrict__ hrep) {
    __shared__ u32 h[4096];
    for (int t = threadIdx.x; t < 4096; t += blockDim.x) h[t] = 0;
    __syncthreads();
    int total_e = R * 11;
    int nq = total_e >> 2;
    int qpb = (nq + (int)gridDim.x - 1) / (int)gridDim.x;
    int start = (int)blockIdx.x * qpb;
    int end = start + qpb; if (end > nq) end = nq;
    int bd = (int)blockDim.x;
    for (int q = start + (int)threadIdx.x; q < end; q += 4 * bd) {
        int q1 = q + bd, q2 = q + 2 * bd, q3 = q + 3 * bd;
        float4 va, vb, vc, vd;
        bool ga = true, gb = q1 < end, gc = q2 < end, gd = q3 < end;
        va = ((const float4*)scores)[q];
        if (gb) vb = ((const float4*)scores)[q1];
        if (gc) vc = ((const float4*)scores)[q2];
        if (gd) vd = ((const float4*)scores)[q3];
#define HPROC(g, qq, v4)                                                   \
        if (g) {                                                           \
            float vv[4] = {v4.x, v4.y, v4.z, v4.w};                        \
            _Pragma("unroll")                                              \
            for (int j = 0; j < 4; j++) {                                  \
                u32 e2 = ((u32)(qq) << 2) + (u32)j;                        \
                u32 r = (u32)(((u64)e2 * MAGIC11) >> 35);                  \
                u32 c = e2 - r * 11u;                                      \
                if (c != 0u) {                                             \
                    float s = __fmul_rn(vv[j], center[r]);                 \
                    if (s > SCORE_THR) {                                   \
                        u32 key = __float_as_uint(s);                      \
                        int b = (int)(key >> 14) - BASE14;                 \
                        b = min(max(b, 0), 4095);                          \
                        atomicAdd(&h[b], 1u);                              \
                    }                                                      \
                }                                                          \
            }                                                              \
        }
        HPROC(ga, q, va) HPROC(gb, q1, vb) HPROC(gc, q2, vc) HPROC(gd, q3, vd)
#undef HPROC
    }
    // tail (total_e % 4) — R*11 % 4 == 0 for R=500000, kept for generality
    if (blockIdx.x == 0 && threadIdx.x == 0) {
        for (int e2 = nq << 2; e2 < total_e; e2++) {
            u32 r = (u32)(((u64)(u32)e2 * MAGIC11) >> 35);
            u32 c = (u32)e2 - r * 11u;
            if (c != 0u) {
                float s = __fmul_rn(scores[e2], center[r]);
                if (s > SCORE_THR) {
                    u32 key = __float_as_uint(s);
                    int b = (int)(key >> 14) - BASE14;
                    b = min(max(b, 0), 4095);
                    atomicAdd(&h[b], 1u);
                }
            }
        }
    }
    __syncthreads();
    u32* hout = hrep + (size_t)(blockIdx.x & (NREP - 1)) * 4096;
    for (int t = threadIdx.x; t < 4096; t += blockDim.x)
        if (h[t]) atomicAdd(&hout[t], h[t]);
}

// ---- scan (one wave): sum 8 replicas (plain loads), suffix offsets, pivot ----
__global__ void k_scan(const u32* __restrict__ hrep, u32* __restrict__ offs,
                       u32* hdr) {
    int lane = threadIdx.x;             // 64 lanes x 64 bins
    int base = 4096 - 64 * (lane + 1);  // lane 0 = topmost segment
    u32 v[64];
    u32 segsum = 0;
#pragma unroll
    for (int j = 0; j < 64; j++) {
        u32 s = 0;
#pragma unroll
        for (int i = 0; i < NREP; i++) s += hrep[i * 4096 + base + j];
        v[j] = s; segsum += s;
    }
    u32 incl = segsum;
    for (int off = 1; off < 64; off <<= 1) {
        u32 t = (u32)__shfl_up((int)incl, off);
        if (lane >= off) incl += t;
    }
    u32 excl = incl - segsum;           // elements in bins above my segment
    u32 total = (u32)__shfl((int)incl, 63);
    u32 run = excl;                     // offs[b] = #elements in bins > b
#pragma unroll
    for (int j = 63; j >= 0; j--) { offs[base + j] = run; run += v[j]; }
    if (lane == 0) hdr[6] = total;
    if (total < (u32)TK) {
        if (lane == 0) { hdr[3] = 0; hdr[5] = total; }   // take-all
        return;
    }
    if ((excl < (u32)TK) && (incl >= (u32)TK)) {
        u32 cum = excl;
#pragma unroll
        for (int j = 63; j >= 0; j--) {
            u32 nc = cum + v[j];
            if (nc >= (u32)TK) { hdr[3] = (u32)(base + j); hdr[5] = nc; break; }
            cum = nc;
        }
    }
}

// ---- collect: contiguous chunks, 4-wide MLP, bucket-scatter >= pivot ----
__global__ void k_collect(const float* __restrict__ scores,
                          const float* __restrict__ center,
                          int R, const u32* __restrict__ hdr,
                          const u32* __restrict__ offs, u32* __restrict__ binpos,
                          u64* __restrict__ buf) {
    u32 thr = hdr[3];
    int total_e = R * 11;
    int nq = total_e >> 2;
    int qpb = (nq + (int)gridDim.x - 1) / (int)gridDim.x;
    int start = (int)blockIdx.x * qpb;
    int end = start + qpb; if (end > nq) end = nq;
    int bd = (int)blockDim.x;
    for (int q = start + (int)threadIdx.x; q < end; q += 4 * bd) {
        int q1 = q + bd, q2 = q + 2 * bd, q3 = q + 3 * bd;
        float4 va, vb, vc, vd;
        bool ga = true, gb = q1 < end, gc = q2 < end, gd = q3 < end;
        va = ((const float4*)scores)[q];
        if (gb) vb = ((const float4*)scores)[q1];
        if (gc) vc = ((const float4*)scores)[q2];
        if (gd) vd = ((const float4*)scores)[q3];
#define CPROC(g, qq, v4)                                                   \
        if (g) {                                                           \
            float vv[4] = {v4.x, v4.y, v4.z, v4.w};                        \
            _Pragma("unroll")                                              \
            for (int j = 0; j < 4; j++) {                                  \
                u32 e2 = ((u32)(qq) << 2) + (u32)j;                        \
                u32 r = (u32)(((u64)e2 * MAGIC11) >> 35);                  \
                u32 c = e2 - r * 11u;                                      \
                if (c != 0u) {                                             \
                    float s = __fmul_rn(vv[j], center[r]);                 \
                    if (s > SCORE_THR) {                                   \
                        u32 key = __float_as_uint(s);                      \
                        int b = (int)(key >> 14) - BASE14;                 \
                        b = min(max(b, 0), 4095);                          \
                        if ((u32)b >= thr) {                               \
                            u32 slot = atomicAdd(&binpos[b], 1u);          \
                            u32 pos = offs[b] + slot;                      \
                            if (pos < CAP) {                               \
                                u32 idx = r * 10u + (c - 1u);              \
                                buf[pos] = ((u64)key << 32) | (u64)(~idx); \
                            }                                              \
                        }                                                  \
                    }                                                      \
                }                                                          \
            }                                                              \
        }
        CPROC(ga, q, va) CPROC(gb, q1, vb) CPROC(gc, q2, vc) CPROC(gd, q3, vd)
#undef CPROC
    }
    if (blockIdx.x == 0 && threadIdx.x == 0) {       // tail (total_e % 4)
        for (int e2 = nq << 2; e2 < total_e; e2++) {
            u32 r = (u32)(((u64)(u32)e2 * MAGIC11) >> 35);
            u32 c = (u32)e2 - r * 11u;
            if (c != 0u) {
                float s = __fmul_rn(scores[e2], center[r]);
                if (s > SCORE_THR) {
                    u32 key = __float_as_uint(s);
                    int b = (int)(key >> 14) - BASE14;
                    b = min(max(b, 0), 4095);
                    if ((u32)b >= thr) {
                        u32 slot = atomicAdd(&binpos[b], 1u);
                        u32 pos = offs[b] + slot;
                        if (pos < CAP) {
                            u32 idx = r * 10u + (c - 1u);
                            buf[pos] = ((u64)key << 32) | (u64)(~idx);
                        }
                    }
                }
            }
        }
    }
}

// ---- per-ELEMENT rank (LDS-staged, O(run) per element) + scatter-write ----
__global__ __launch_bounds__(1024) void k_rank(
        const float* __restrict__ boxes, const u32* __restrict__ offs,
        const u32* __restrict__ hdr, const u64* __restrict__ buf,
        float* __restrict__ cand_bx, float* __restrict__ nms_bx,
        float* __restrict__ vals) {
    __shared__ u64 kb[CAP];
    __shared__ u32 lo[4096];
    int tid = threadIdx.x;
    u32 n = hdr[5]; if (n > (u32)CAP) n = CAP;
    u32 total = hdr[6];
    for (int t = tid; t < CAP; t += 1024) kb[t] = (t < (int)n) ? buf[t] : 0ull;
    for (int t = tid; t < 4096; t += 1024) lo[t] = offs[t];
    __syncthreads();
    for (int i = tid; i < (int)n; i += 1024) {
        u64 x = kb[i];
        u32 key = (u32)(x >> 32);
        int b = (int)(key >> 14) - BASE14;
        b = min(max(b, 0), 4095);
        u32 start = lo[b];
        u32 end = (b > 0) ? lo[b - 1] : total;
        if (end > (u32)CAP) end = CAP;
        u32 rk = start;                 // global rank = bin start + within-bin rank
        for (u32 j = start; j < end; j++) rk += (kb[j] > x) ? 1u : 0u;
        if (rk < (u32)TK) {
            u32 idx = ~(u32)x;
            u32 r = idx / 10u, cls = idx % 10u;
            const float* bp = boxes + (size_t)r * 4;
            float c0 = fminf(fmaxf(bp[0], 0.f), 1920.f);
            float c1 = fminf(fmaxf(bp[1], 0.f), 1080.f);
            float c2 = fminf(fmaxf(bp[2], 0.f), 1920.f);
            float c3 = fminf(fmaxf(bp[3], 0.f), 1080.f);
            float offv = __fmul_rn((float)cls, 3001.0f);  // exact: small ints
            cand_bx[rk * 4 + 0] = c0; cand_bx[rk * 4 + 1] = c1;
            cand_bx[rk * 4 + 2] = c2; cand_bx[rk * 4 + 3] = c3;
            nms_bx[rk * 4 + 0] = __fadd_rn(c0, offv);
            nms_bx[rk * 4 + 1] = __fadd_rn(c1, offv);
            nms_bx[rk * 4 + 2] = __fadd_rn(c2, offv);
            nms_bx[rk * 4 + 3] = __fadd_rn(c3, offv);
            vals[rk] = __uint_as_float(key);
        }
    }
}

// ---- suppression bitmask, COLUMN-major: maskT[colword][row] ----
__global__ void k_mask(const float* __restrict__ nms_bx, u32* __restrict__ maskT) {
    __shared__ float4 cb[64];
    __shared__ float ca[64];
    int tid = threadIdx.x;
    int colbase = blockIdx.x * 64, rowbase = blockIdx.y * 64;
    float4 c = ((const float4*)nms_bx)[colbase + tid];
    cb[tid] = c;
    ca[tid] = __fmul_rn(fmaxf(__fsub_rn(c.z, c.x), 0.f),
                        fmaxf(__fsub_rn(c.w, c.y), 0.f));
    int row = rowbase + tid;
    float4 rb = ((const float4*)nms_bx)[row];
    float rarea = __fmul_rn(fmaxf(__fsub_rn(rb.z, rb.x), 0.f),
                            fmaxf(__fsub_rn(rb.w, rb.y), 0.f));
    __syncthreads();
    u32 w0 = 0, w1 = 0;
    for (int cc = 0; cc < 64; cc++) {
        int col = colbase + cc;
        if (col > row) {
            float4 cbv = cb[cc];
            float ltx = fmaxf(rb.x, cbv.x), lty = fmaxf(rb.y, cbv.y);
            float rbx = fminf(rb.z, cbv.z), rby = fminf(rb.w, cbv.w);
            float w = fmaxf(__fsub_rn(rbx, ltx), 0.f);
            float h = fmaxf(__fsub_rn(rby, lty), 0.f);
            float inter = __fmul_rn(w, h);
            // ref order: ((area_i + area_j) - inter) + 1e-9
            float denom = __fadd_rn(__fsub_rn(__fadd_rn(rarea, ca[cc]), inter), 1e-9f);
            float iou = __fdiv_rn(inter, denom);
            if (iou > NMS_THR) {
                if (cc < 32) w0 |= 1u << cc; else w1 |= 1u << (cc - 32);
            }
        }
    }
    maskT[(blockIdx.x * 2 + 0) * 2048 + row] = w0;
    maskT[(blockIdx.x * 2 + 1) * 2048 + row] = w1;
}

// ---- greedy scan: wave 0 scans from LDS; waves 1-15 prefetch maskT chunks ----
__global__ __launch_bounds__(1024) void k_final(
        const u32* __restrict__ maskT, const float* __restrict__ vals,
        const float* __restrict__ cand_bx, float* __restrict__ out) {
    // lds tile layout: [buf][word-in-chunk][j][lane]  (read bank = lane%32, 2-way free)
    __shared__ u32 lds[2 * CHUNK * 2048];   // 48 KB
    int tid = threadIdx.x;

    // producer: copy words [3c, 3c+nw) into buf c&1
#define PRODUCE(c)                                                          \
    {                                                                       \
        int nw = 64 - 3 * (c); if (nw > CHUNK) nw = CHUNK;                  \
        int elems = nw << 9;                                                \
        int pid = tid - 64;                                                 \
        u32* dst0 = lds + ((c) & 1) * (CHUNK * 2048);                       \
        for (int i = pid; i < elems; i += 960) {                            \
            int wp = i >> 9, rem = i & 511;                                 \
            int l = rem >> 3, jq = rem & 7;                                 \
            const uint4 U = *(const uint4*)(maskT + l * 2048 +              \
                                            32 * (3 * (c) + wp) + 4 * jq);  \
            u32* d = dst0 + wp * 2048 + (4 * jq) * 64 + l;                  \
            d[0] = U.x; d[64] = U.y; d[128] = U.z; d[192] = U.w;            \
        }                                                                   \
    }

    int lane = tid;  // valid only for tid < 64
    float4 vv[8];
    u32 validw = 0, removed = 0, keepw = 0;
    if (tid < 64) {
        const float4* vp = (const float4*)vals + (size_t)lane * 8;
#pragma unroll
        for (int j = 0; j < 8; j++) vv[j] = vp[j];
#pragma unroll
        for (int j = 0; j < 8; j++) {
            validw |= (vv[j].x > SCORE_THR ? 1u : 0u) << (4 * j + 0);
            validw |= (vv[j].y > SCORE_THR ? 1u : 0u) << (4 * j + 1);
            validw |= (vv[j].z > SCORE_THR ? 1u : 0u) << (4 * j + 2);
            validw |= (vv[j].w > SCORE_THR ? 1u : 0u) << (4 * j + 3);
        }
    } else {
        PRODUCE(0)
    }
    __syncthreads();
    for (int c = 0; c < NCHUNK; c++) {
        if (tid >= 64) {
            if (c + 1 < NCHUNK) PRODUCE(c + 1)
        } else {
            int nw = 64 - 3 * c; if (nw > CHUNK) nw = CHUNK;
            const u32* src0 = lds + (c & 1) * (CHUNK * 2048) + lane;
            for (int wp = 0; wp < nw; wp++) {
                int w = 3 * c + wp;
                const u32* src = src0 + wp * 2048;
                u32 rw[32];
#pragma unroll
                for (int j = 0; j < 32; j++) rw[j] = src[j * 64];
                u32 alive = validw & ~removed;
#pragma unroll
                for (int j = 0; j < 32; j++)
                    alive &= ((alive >> j) & 1u) ? ~rw[j] : 0xFFFFFFFFu;
                u32 kw = (u32)__shfl((int)alive, w);
                if (lane == w) keepw = kw;
                u32 acc = 0;
#pragma unroll
                for (int j = 0; j < 32; j++) acc |= ((kw >> j) & 1u) ? rw[j] : 0u;
                removed |= acc;
            }
        }
        __syncthreads();
    }
#undef PRODUCE
    if (tid < 64) {
#pragma unroll
        for (int b = 0; b < 32; b++) {
            int i = lane * 32 + b;
            bool kp = (keepw >> b) & 1u;
            const float4 bx = ((const float4*)cand_bx)[i];
            float v = (b & 3) == 0 ? vv[b >> 2].x :
                      (b & 3) == 1 ? vv[b >> 2].y :
                      (b & 3) == 2 ? vv[b >> 2].z : vv[b >> 2].w;
            out[i * 5 + 0] = kp ? bx.x : 0.f;
            out[i * 5 + 1] = kp ? bx.y : 0.f;
            out[i * 5 + 2] = kp ? bx.z : 0.f;
            out[i * 5 + 3] = kp ? bx.w : 0.f;
            out[i * 5 + 4] = kp ? v : 0.f;
        }
    }
}

extern "C" void kernel_launch(void* const* d_in, const int* in_sizes, int n_in,
                              void* d_out, int out_size, void* d_ws, size_t ws_size,
                              hipStream_t stream) {
    const float* boxes = (const float*)d_in[0];
    const float* scores = (const float*)d_in[1];
    const float* center = (const float*)d_in[2];
    float* out = (float*)d_out;
    int R = in_sizes[2];

    char* w = (char*)d_ws;
    u32* offs   = (u32*)(w + WS_OFFS);
    u32* binpos = (u32*)(w + WS_BINPOS);
    u32* hdr    = (u32*)(w + WS_HDR);
    float* cbx  = (float*)(w + WS_CBX);
    float* nbx  = (float*)(w + WS_NBX);
    float* vls  = (float*)(w + WS_VALS);
    u32* maskT  = (u32*)(w + WS_MASK);
    u32* hrep   = (u32*)(w + WS_HREP);  // aliases maskT[0:128K]  (dead after k_scan)
    u64* buf    = (u64*)(w + WS_BUF);   // aliases maskT[128K:160K] (dead before k_mask)

    // zero binpos+hdr+cand/nms/vals padding + hrep (offs is fully written by k_scan)
    hipMemsetAsync(w + WS_BINPOS, 0, WS_BUF - WS_BINPOS, stream);

    k_hist<<<256, 256, 0, stream>>>(scores, center, R, hrep);
    k_scan<<<1, 64, 0, stream>>>(hrep, offs, hdr);
    k_collect<<<256, 256, 0, stream>>>(scores, center, R, hdr, offs, binpos, buf);
    k_rank<<<1, 1024, 0, stream>>>(boxes, offs, hdr, buf, cbx, nbx, vls);
    k_mask<<<dim3(32, 32), 64, 0, stream>>>(nbx, maskT);
    k_final<<<1, 1024, 0, stream>>>(maskT, vls, cbx, out);
}

// Round 9
// 153.417 us; speedup vs baseline: 1.2987x; 1.2987x over previous
//
#include <hip/hip_runtime.h>
#include <stdint.h>

typedef unsigned int u32;
typedef unsigned long long u64;

#define SCORE_THR 0.05f
#define NMS_THR   0.5f
#define TK        2048
#define CAP       4096
#define BASE14    ((int)(0x3D4CCCCDu >> 14))   // (bits of 0.05f) >> 14 = 62771
#define MAGIC11   3123612579ull                // ceil(2^35/11); exact /11 for e < 2^35
#define NREP      8
#define PAIR_CAP  16384

// ---------------- ws layout (bytes) ----------------
// 0      : offs    u32[4096]  (fully written by k_scan -> NOT memset)
// 16384  : binpos  u32[4096]  (zeroed)
// 32768  : hdr     u32[64]    (zeroed) hdr[3]=pivot hdr[5]=n hdr[6]=total hdr[8]=pair cnt
// 33024  : cand_bx f32[2048*4] (zeroed: padding slots)
// 65792  : nms_bx  f32[2048*4] (zeroed)
// 98560  : vals    f32[2048]   (zeroed)
// 106752 : hrep    u32[8][4096] (128 KB, zeroed; dead after k_scan)
// 237824 : buf     u64[4096]    (32 KB; every slot [0,n) written by k_collect)
// 269824 : pairs   u32[16384]   (64 KB; no memset needed — clamped by hdr[8])
// total 335360 B
#define WS_OFFS   0
#define WS_BINPOS 16384
#define WS_HDR    32768
#define WS_CBX    33024
#define WS_NBX    65792
#define WS_VALS   98560
#define WS_HREP   106752
#define WS_BUF    237824
#define WS_PAIRS  269824

// ---- histogram over key bits [30:14]: contiguous chunks, 4-wide float4 MLP,
//      LDS hist, merge into 8 replicated global hists (contention /8) ----
__global__ void k_hist(const float* __restrict__ scores,
                       const float* __restrict__ center,
                       int R, u32* __restrict__ hrep) {
    __shared__ u32 h[4096];
    for (int t = threadIdx.x; t < 4096; t += blockDim.x) h[t] = 0;
    __syncthreads();
    int total_e = R * 11;
    int nq = total_e >> 2;
    int qpb = (nq + (int)gridDim.x - 1) / (int)gridDim.x;
    int start = (int)blockIdx.x * qpb;
    int end = start + qpb; if (end > nq) end = nq;
    int bd = (int)blockDim.x;
    for (int q = start + (int)threadIdx.x; q < end; q += 4 * bd) {
        int q1 = q + bd, q2 = q + 2 * bd, q3 = q + 3 * bd;
        float4 va, vb, vc, vd;
        bool ga = true, gb = q1 < end, gc = q2 < end, gd = q3 < end;
        va = ((const float4*)scores)[q];
        if (gb) vb = ((const float4*)scores)[q1];
        if (gc) vc = ((const float4*)scores)[q2];
        if (gd) vd = ((const float4*)scores)[q3];
#define HPROC(g, qq, v4)                                                   \
        if (g) {                                                           \
            float vv[4] = {v4.x, v4.y, v4.z, v4.w};                        \
            _Pragma("unroll")                                              \
            for (int j = 0; j < 4; j++) {                                  \
                u32 e2 = ((u32)(qq) << 2) + (u32)j;                        \
                u32 r = (u32)(((u64)e2 * MAGIC11) >> 35);                  \
                u32 c = e2 - r * 11u;                                      \
                if (c != 0u) {                                             \
                    float s = __fmul_rn(vv[j], center[r]);                 \
                    if (s > SCORE_THR) {                                   \
                        u32 key = __float_as_uint(s);                      \
                        int b = (int)(key >> 14) - BASE14;                 \
                        b = min(max(b, 0), 4095);                          \
                        atomicAdd(&h[b], 1u);                              \
                    }                                                      \
                }                                                          \
            }                                                              \
        }
        HPROC(ga, q, va) HPROC(gb, q1, vb) HPROC(gc, q2, vc) HPROC(gd, q3, vd)
#undef HPROC
    }
    // tail (total_e % 4) — R*11 % 4 == 0 for R=500000, kept for generality
    if (blockIdx.x == 0 && threadIdx.x == 0) {
        for (int e2 = nq << 2; e2 < total_e; e2++) {
            u32 r = (u32)(((u64)(u32)e2 * MAGIC11) >> 35);
            u32 c = (u32)e2 - r * 11u;
            if (c != 0u) {
                float s = __fmul_rn(scores[e2], center[r]);
                if (s > SCORE_THR) {
                    u32 key = __float_as_uint(s);
                    int b = (int)(key >> 14) - BASE14;
                    b = min(max(b, 0), 4095);
                    atomicAdd(&h[b], 1u);
                }
            }
        }
    }
    __syncthreads();
    u32* hout = hrep + (size_t)(blockIdx.x & (NREP - 1)) * 4096;
    for (int t = threadIdx.x; t < 4096; t += blockDim.x)
        if (h[t]) atomicAdd(&hout[t], h[t]);
}

// ---- scan (one wave): sum 8 replicas (plain loads), suffix offsets, pivot ----
__global__ void k_scan(const u32* __restrict__ hrep, u32* __restrict__ offs,
                       u32* hdr) {
    int lane = threadIdx.x;             // 64 lanes x 64 bins
    int base = 4096 - 64 * (lane + 1);  // lane 0 = topmost segment
    u32 v[64];
    u32 segsum = 0;
#pragma unroll
    for (int j = 0; j < 64; j++) {
        u32 s = 0;
#pragma unroll
        for (int i = 0; i < NREP; i++) s += hrep[i * 4096 + base + j];
        v[j] = s; segsum += s;
    }
    u32 incl = segsum;
    for (int off = 1; off < 64; off <<= 1) {
        u32 t = (u32)__shfl_up((int)incl, off);
        if (lane >= off) incl += t;
    }
    u32 excl = incl - segsum;           // elements in bins above my segment
    u32 total = (u32)__shfl((int)incl, 63);
    u32 run = excl;                     // offs[b] = #elements in bins > b
#pragma unroll
    for (int j = 63; j >= 0; j--) { offs[base + j] = run; run += v[j]; }
    if (lane == 0) hdr[6] = total;
    if (total < (u32)TK) {
        if (lane == 0) { hdr[3] = 0; hdr[5] = total; }   // take-all
        return;
    }
    if ((excl < (u32)TK) && (incl >= (u32)TK)) {
        u32 cum = excl;
#pragma unroll
        for (int j = 63; j >= 0; j--) {
            u32 nc = cum + v[j];
            if (nc >= (u32)TK) { hdr[3] = (u32)(base + j); hdr[5] = nc; break; }
            cum = nc;
        }
    }
}

// ---- collect: contiguous chunks, 4-wide MLP, bucket-scatter >= pivot ----
__global__ void k_collect(const float* __restrict__ scores,
                          const float* __restrict__ center,
                          int R, const u32* __restrict__ hdr,
                          const u32* __restrict__ offs, u32* __restrict__ binpos,
                          u64* __restrict__ buf) {
    u32 thr = hdr[3];
    int total_e = R * 11;
    int nq = total_e >> 2;
    int qpb = (nq + (int)gridDim.x - 1) / (int)gridDim.x;
    int start = (int)blockIdx.x * qpb;
    int end = start + qpb; if (end > nq) end = nq;
    int bd = (int)blockDim.x;
    for (int q = start + (int)threadIdx.x; q < end; q += 4 * bd) {
        int q1 = q + bd, q2 = q + 2 * bd, q3 = q + 3 * bd;
        float4 va, vb, vc, vd;
        bool ga = true, gb = q1 < end, gc = q2 < end, gd = q3 < end;
        va = ((const float4*)scores)[q];
        if (gb) vb = ((const float4*)scores)[q1];
        if (gc) vc = ((const float4*)scores)[q2];
        if (gd) vd = ((const float4*)scores)[q3];
#define CPROC(g, qq, v4)                                                   \
        if (g) {                                                           \
            float vv[4] = {v4.x, v4.y, v4.z, v4.w};                        \
            _Pragma("unroll")                                              \
            for (int j = 0; j < 4; j++) {                                  \
                u32 e2 = ((u32)(qq) << 2) + (u32)j;                        \
                u32 r = (u32)(((u64)e2 * MAGIC11) >> 35);                  \
                u32 c = e2 - r * 11u;                                      \
                if (c != 0u) {                                             \
                    float s = __fmul_rn(vv[j], center[r]);                 \
                    if (s > SCORE_THR) {                                   \
                        u32 key = __float_as_uint(s);                      \
                        int b = (int)(key >> 14) - BASE14;                 \
                        b = min(max(b, 0), 4095);                          \
                        if ((u32)b >= thr) {                               \
                            u32 slot = atomicAdd(&binpos[b], 1u);          \
                            u32 pos = offs[b] + slot;                      \
                            if (pos < CAP) {                               \
                                u32 idx = r * 10u + (c - 1u);              \
                                buf[pos] = ((u64)key << 32) | (u64)(~idx); \
                            }                                              \
                        }                                                  \
                    }                                                      \
                }                                                          \
            }                                                              \
        }
        CPROC(ga, q, va) CPROC(gb, q1, vb) CPROC(gc, q2, vc) CPROC(gd, q3, vd)
#undef CPROC
    }
    if (blockIdx.x == 0 && threadIdx.x == 0) {       // tail (total_e % 4)
        for (int e2 = nq << 2; e2 < total_e; e2++) {
            u32 r = (u32)(((u64)(u32)e2 * MAGIC11) >> 35);
            u32 c = (u32)e2 - r * 11u;
            if (c != 0u) {
                float s = __fmul_rn(scores[e2], center[r]);
                if (s > SCORE_THR) {
                    u32 key = __float_as_uint(s);
                    int b = (int)(key >> 14) - BASE14;
                    b = min(max(b, 0), 4095);
                    if ((u32)b >= thr) {
                        u32 slot = atomicAdd(&binpos[b], 1u);
                        u32 pos = offs[b] + slot;
                        if (pos < CAP) {
                            u32 idx = r * 10u + (c - 1u);
                            buf[pos] = ((u64)key << 32) | (u64)(~idx);
                        }
                    }
                }
            }
        }
    }
}

// ---- per-ELEMENT rank (LDS-staged, O(run) per element) + scatter-write ----
__global__ __launch_bounds__(1024) void k_rank(
        const float* __restrict__ boxes, const u32* __restrict__ offs,
        const u32* __restrict__ hdr, const u64* __restrict__ buf,
        float* __restrict__ cand_bx, float* __restrict__ nms_bx,
        float* __restrict__ vals) {
    __shared__ u64 kb[CAP];
    __shared__ u32 lo[4096];
    int tid = threadIdx.x;
    u32 n = hdr[5]; if (n > (u32)CAP) n = CAP;
    u32 total = hdr[6];
    for (int t = tid; t < CAP; t += 1024) kb[t] = (t < (int)n) ? buf[t] : 0ull;
    for (int t = tid; t < 4096; t += 1024) lo[t] = offs[t];
    __syncthreads();
    for (int i = tid; i < (int)n; i += 1024) {
        u64 x = kb[i];
        u32 key = (u32)(x >> 32);
        int b = (int)(key >> 14) - BASE14;
        b = min(max(b, 0), 4095);
        u32 start = lo[b];
        u32 end = (b > 0) ? lo[b - 1] : total;
        if (end > (u32)CAP) end = CAP;
        u32 rk = start;                 // global rank = bin start + within-bin rank
        for (u32 j = start; j < end; j++) rk += (kb[j] > x) ? 1u : 0u;
        if (rk < (u32)TK) {
            u32 idx = ~(u32)x;
            u32 r = idx / 10u, cls = idx % 10u;
            const float* bp = boxes + (size_t)r * 4;
            float c0 = fminf(fmaxf(bp[0], 0.f), 1920.f);
            float c1 = fminf(fmaxf(bp[1], 0.f), 1080.f);
            float c2 = fminf(fmaxf(bp[2], 0.f), 1920.f);
            float c3 = fminf(fmaxf(bp[3], 0.f), 1080.f);
            float offv = __fmul_rn((float)cls, 3001.0f);  // exact: small ints
            cand_bx[rk * 4 + 0] = c0; cand_bx[rk * 4 + 1] = c1;
            cand_bx[rk * 4 + 2] = c2; cand_bx[rk * 4 + 3] = c3;
            nms_bx[rk * 4 + 0] = __fadd_rn(c0, offv);
            nms_bx[rk * 4 + 1] = __fadd_rn(c1, offv);
            nms_bx[rk * 4 + 2] = __fadd_rn(c2, offv);
            nms_bx[rk * 4 + 3] = __fadd_rn(c3, offv);
            vals[rk] = __uint_as_float(key);
        }
    }
}

// ---- suppression PAIRS (sparse): append (row<<11|col) for iou>thr, col>row ----
__global__ void k_mask(const float* __restrict__ nms_bx, u32* __restrict__ hdr,
                       u32* __restrict__ pairs) {
    int colbase = blockIdx.x * 64, rowbase = blockIdx.y * 64;
    if (colbase + 63 <= rowbase) return;   // whole tile has col <= row
    __shared__ float4 cb[64];
    __shared__ float ca[64];
    int tid = threadIdx.x;
    float4 c = ((const float4*)nms_bx)[colbase + tid];
    cb[tid] = c;
    ca[tid] = __fmul_rn(fmaxf(__fsub_rn(c.z, c.x), 0.f),
                        fmaxf(__fsub_rn(c.w, c.y), 0.f));
    int row = rowbase + tid;
    float4 rb = ((const float4*)nms_bx)[row];
    float rarea = __fmul_rn(fmaxf(__fsub_rn(rb.z, rb.x), 0.f),
                            fmaxf(__fsub_rn(rb.w, rb.y), 0.f));
    __syncthreads();
    for (int cc = 0; cc < 64; cc++) {
        int col = colbase + cc;
        if (col > row) {
            float4 cbv = cb[cc];
            float ltx = fmaxf(rb.x, cbv.x), lty = fmaxf(rb.y, cbv.y);
            float rbx = fminf(rb.z, cbv.z), rby = fminf(rb.w, cbv.w);
            float w = fmaxf(__fsub_rn(rbx, ltx), 0.f);
            float h = fmaxf(__fsub_rn(rby, lty), 0.f);
            float inter = __fmul_rn(w, h);
            // ref order: ((area_i + area_j) - inter) + 1e-9
            float denom = __fadd_rn(__fsub_rn(__fadd_rn(rarea, ca[cc]), inter), 1e-9f);
            float iou = __fdiv_rn(inter, denom);
            if (iou > NMS_THR) {
                u32 p = atomicAdd(&hdr[8], 1u);
                if (p < PAIR_CAP)
                    pairs[p] = ((u32)row << 11) | (u32)col;
            }
        }
    }
}

// ---- greedy scan over SPARSE pairs (one wave): counting-sort by row in LDS,
//      then exact serial greedy; keep = valid & ~removed (rows only suppressed
//      by earlier rows, so post-hoc evaluation is exact) ----
__global__ __launch_bounds__(64) void k_final(
        const u32* __restrict__ pairs, const u32* __restrict__ hdr,
        const float* __restrict__ vals, const float* __restrict__ cand_bx,
        float* __restrict__ out) {
    __shared__ u32 sp[PAIR_CAP];
    __shared__ u32 cur[2048];
    int lane = threadIdx.x;
    u32 np = hdr[8]; if (np > (u32)PAIR_CAP) np = PAIR_CAP;
    const float4* vp = (const float4*)vals + (size_t)lane * 8;
    float4 vv[8];
#pragma unroll
    for (int j = 0; j < 8; j++) vv[j] = vp[j];
    u32 validw = 0;
#pragma unroll
    for (int j = 0; j < 8; j++) {
        validw |= (vv[j].x > SCORE_THR ? 1u : 0u) << (4 * j + 0);
        validw |= (vv[j].y > SCORE_THR ? 1u : 0u) << (4 * j + 1);
        validw |= (vv[j].z > SCORE_THR ? 1u : 0u) << (4 * j + 2);
        validw |= (vv[j].w > SCORE_THR ? 1u : 0u) << (4 * j + 3);
    }
    for (int t = lane; t < 2048; t += 64) cur[t] = 0;
    __syncthreads();
    for (u32 k = lane; k < np; k += 64) atomicAdd(&cur[pairs[k] >> 11], 1u);
    __syncthreads();
    // ascending prefix sum: lane owns rows [32*lane, 32*lane+32)
    u32 cnt[32];
    u32 seg = 0;
#pragma unroll
    for (int j = 0; j < 32; j++) { cnt[j] = cur[lane * 32 + j]; seg += cnt[j]; }
    u32 incl = seg;
    for (int off = 1; off < 64; off <<= 1) {
        u32 t = (u32)__shfl_up((int)incl, off);
        if (lane >= off) incl += t;
    }
    u32 run = incl - seg;
#pragma unroll
    for (int j = 0; j < 32; j++) { cur[lane * 32 + j] = run; run += cnt[j]; }
    __syncthreads();
    for (u32 k = lane; k < np; k += 64) {
        u32 p = pairs[k];
        u32 pos = atomicAdd(&cur[p >> 11], 1u);
        sp[pos] = p;
    }
    __syncthreads();
    // exact greedy: pairs sorted by row ascending; cols always > row
    u32 removed = 0;
    for (u32 k = 0; k < np; k++) {
        u32 p = sp[k];
        u32 row = p >> 11, col = p & 2047u;
        u32 aw = (u32)__shfl((int)(validw & ~removed), (int)(row >> 5));
        if ((aw >> (row & 31)) & 1u)
            if (lane == (int)(col >> 5)) removed |= 1u << (col & 31);
    }
    u32 keepw = validw & ~removed;
#pragma unroll
    for (int b = 0; b < 32; b++) {
        int i = lane * 32 + b;
        bool kp = (keepw >> b) & 1u;
        const float4 bx = ((const float4*)cand_bx)[i];
        float v = (b & 3) == 0 ? vv[b >> 2].x :
                  (b & 3) == 1 ? vv[b >> 2].y :
                  (b & 3) == 2 ? vv[b >> 2].z : vv[b >> 2].w;
        out[i * 5 + 0] = kp ? bx.x : 0.f;
        out[i * 5 + 1] = kp ? bx.y : 0.f;
        out[i * 5 + 2] = kp ? bx.z : 0.f;
        out[i * 5 + 3] = kp ? bx.w : 0.f;
        out[i * 5 + 4] = kp ? v : 0.f;
    }
}

extern "C" void kernel_launch(void* const* d_in, const int* in_sizes, int n_in,
                              void* d_out, int out_size, void* d_ws, size_t ws_size,
                              hipStream_t stream) {
    const float* boxes = (const float*)d_in[0];
    const float* scores = (const float*)d_in[1];
    const float* center = (const float*)d_in[2];
    float* out = (float*)d_out;
    int R = in_sizes[2];

    char* w = (char*)d_ws;
    u32* offs   = (u32*)(w + WS_OFFS);
    u32* binpos = (u32*)(w + WS_BINPOS);
    u32* hdr    = (u32*)(w + WS_HDR);
    float* cbx  = (float*)(w + WS_CBX);
    float* nbx  = (float*)(w + WS_NBX);
    float* vls  = (float*)(w + WS_VALS);
    u32* hrep   = (u32*)(w + WS_HREP);
    u64* buf    = (u64*)(w + WS_BUF);
    u32* pairs  = (u32*)(w + WS_PAIRS);

    // zero binpos+hdr+cand/nms/vals padding+hrep (offs fully written by k_scan;
    // buf fully written by k_collect; pairs clamped by hdr[8])
    hipMemsetAsync(w + WS_BINPOS, 0, WS_BUF - WS_BINPOS, stream);

    k_hist<<<256, 256, 0, stream>>>(scores, center, R, hrep);
    k_scan<<<1, 64, 0, stream>>>(hrep, offs, hdr);
    k_collect<<<256, 256, 0, stream>>>(scores, center, R, hdr, offs, binpos, buf);
    k_rank<<<1, 1024, 0, stream>>>(boxes, offs, hdr, buf, cbx, nbx, vls);
    k_mask<<<dim3(32, 32), 64, 0, stream>>>(nbx, hdr, pairs);
    k_final<<<1, 64, 0, stream>>>(pairs, hdr, vls, cbx, out);
}

// Round 10
// 141.242 us; speedup vs baseline: 1.4107x; 1.0862x over previous
//
#include <hip/hip_runtime.h>
#include <stdint.h>

typedef unsigned int u32;
typedef unsigned long long u64;

#define SCORE_THR 0.05f
#define NMS_THR   0.5f
#define TK        2048
#define CAP       4096
#define BASE14    ((int)(0x3D4CCCCDu >> 14))   // (bits of 0.05f) >> 14 = 62771
#define MAGIC11   3123612579ull                // ceil(2^35/11); exact /11 for e < 2^35
#define NREP      8
#define PAIR_CAP  16384
#define SGRID     1024                         // streaming grid: 4 blocks/CU

// ---------------- ws layout (bytes) ----------------
// 0      : offs    u32[4096]  (fully written by k_scan -> NOT memset)
// 16384  : binpos  u32[4096]  (zeroed)
// 32768  : hdr     u32[64]    (zeroed) hdr[3]=pivot hdr[5]=n hdr[6]=total hdr[8]=pair cnt
// 33024  : cand_bx f32[2048*4] (zeroed: padding slots)
// 65792  : nms_bx  f32[2048*4] (zeroed)
// 98560  : vals    f32[2048]   (zeroed)
// 106752 : hrep    u32[8][4096] (128 KB, zeroed; dead after k_scan)
// 237824 : buf     u64[4096]    (32 KB; every slot [0,n) written by k_collect)
// 269824 : pairs   u32[16384]   (64 KB; no memset needed — clamped by hdr[8])
// total 335360 B
#define WS_OFFS   0
#define WS_BINPOS 16384
#define WS_HDR    32768
#define WS_CBX    33024
#define WS_NBX    65792
#define WS_VALS   98560
#define WS_HREP   106752
#define WS_BUF    237824
#define WS_PAIRS  269824

// ---- histogram over key bits [30:14]: contiguous chunks, 4-wide float4 MLP,
//      LDS hist, merge into 8 replicated global hists (contention /8) ----
__global__ void k_hist(const float* __restrict__ scores,
                       const float* __restrict__ center,
                       int R, u32* __restrict__ hrep) {
    __shared__ u32 h[4096];
    for (int t = threadIdx.x; t < 4096; t += blockDim.x) h[t] = 0;
    __syncthreads();
    int total_e = R * 11;
    int nq = total_e >> 2;
    int qpb = (nq + (int)gridDim.x - 1) / (int)gridDim.x;
    int start = (int)blockIdx.x * qpb;
    int end = start + qpb; if (end > nq) end = nq;
    int bd = (int)blockDim.x;
    for (int q = start + (int)threadIdx.x; q < end; q += 4 * bd) {
        int q1 = q + bd, q2 = q + 2 * bd, q3 = q + 3 * bd;
        float4 va, vb, vc, vd;
        bool ga = true, gb = q1 < end, gc = q2 < end, gd = q3 < end;
        va = ((const float4*)scores)[q];
        if (gb) vb = ((const float4*)scores)[q1];
        if (gc) vc = ((const float4*)scores)[q2];
        if (gd) vd = ((const float4*)scores)[q3];
#define HPROC(g, qq, v4)                                                   \
        if (g) {                                                           \
            float vv[4] = {v4.x, v4.y, v4.z, v4.w};                        \
            _Pragma("unroll")                                              \
            for (int j = 0; j < 4; j++) {                                  \
                u32 e2 = ((u32)(qq) << 2) + (u32)j;                        \
                u32 r = (u32)(((u64)e2 * MAGIC11) >> 35);                  \
                u32 c = e2 - r * 11u;                                      \
                if (c != 0u) {                                             \
                    float s = __fmul_rn(vv[j], center[r]);                 \
                    if (s > SCORE_THR) {                                   \
                        u32 key = __float_as_uint(s);                      \
                        int b = (int)(key >> 14) - BASE14;                 \
                        b = min(max(b, 0), 4095);                          \
                        atomicAdd(&h[b], 1u);                              \
                    }                                                      \
                }                                                          \
            }                                                              \
        }
        HPROC(ga, q, va) HPROC(gb, q1, vb) HPROC(gc, q2, vc) HPROC(gd, q3, vd)
#undef HPROC
    }
    // tail (total_e % 4) — R*11 % 4 == 0 for R=500000, kept for generality
    if (blockIdx.x == 0 && threadIdx.x == 0) {
        for (int e2 = nq << 2; e2 < total_e; e2++) {
            u32 r = (u32)(((u64)(u32)e2 * MAGIC11) >> 35);
            u32 c = (u32)e2 - r * 11u;
            if (c != 0u) {
                float s = __fmul_rn(scores[e2], center[r]);
                if (s > SCORE_THR) {
                    u32 key = __float_as_uint(s);
                    int b = (int)(key >> 14) - BASE14;
                    b = min(max(b, 0), 4095);
                    atomicAdd(&h[b], 1u);
                }
            }
        }
    }
    __syncthreads();
    u32* hout = hrep + (size_t)(blockIdx.x & (NREP - 1)) * 4096;
    for (int t = threadIdx.x; t < 4096; t += blockDim.x)
        if (h[t]) atomicAdd(&hout[t], h[t]);
}

// ---- scan (one wave): sum 8 replicas (plain loads), suffix offsets, pivot ----
__global__ void k_scan(const u32* __restrict__ hrep, u32* __restrict__ offs,
                       u32* hdr) {
    int lane = threadIdx.x;             // 64 lanes x 64 bins
    int base = 4096 - 64 * (lane + 1);  // lane 0 = topmost segment
    u32 v[64];
    u32 segsum = 0;
#pragma unroll
    for (int j = 0; j < 64; j++) {
        u32 s = 0;
#pragma unroll
        for (int i = 0; i < NREP; i++) s += hrep[i * 4096 + base + j];
        v[j] = s; segsum += s;
    }
    u32 incl = segsum;
    for (int off = 1; off < 64; off <<= 1) {
        u32 t = (u32)__shfl_up((int)incl, off);
        if (lane >= off) incl += t;
    }
    u32 excl = incl - segsum;           // elements in bins above my segment
    u32 total = (u32)__shfl((int)incl, 63);
    u32 run = excl;                     // offs[b] = #elements in bins > b
#pragma unroll
    for (int j = 63; j >= 0; j--) { offs[base + j] = run; run += v[j]; }
    if (lane == 0) hdr[6] = total;
    if (total < (u32)TK) {
        if (lane == 0) { hdr[3] = 0; hdr[5] = total; }   // take-all
        return;
    }
    if ((excl < (u32)TK) && (incl >= (u32)TK)) {
        u32 cum = excl;
#pragma unroll
        for (int j = 63; j >= 0; j--) {
            u32 nc = cum + v[j];
            if (nc >= (u32)TK) { hdr[3] = (u32)(base + j); hdr[5] = nc; break; }
            cum = nc;
        }
    }
}

// ---- collect: contiguous chunks, 4-wide MLP, bucket-scatter >= pivot ----
__global__ void k_collect(const float* __restrict__ scores,
                          const float* __restrict__ center,
                          int R, const u32* __restrict__ hdr,
                          const u32* __restrict__ offs, u32* __restrict__ binpos,
                          u64* __restrict__ buf) {
    u32 thr = hdr[3];
    int total_e = R * 11;
    int nq = total_e >> 2;
    int qpb = (nq + (int)gridDim.x - 1) / (int)gridDim.x;
    int start = (int)blockIdx.x * qpb;
    int end = start + qpb; if (end > nq) end = nq;
    int bd = (int)blockDim.x;
    for (int q = start + (int)threadIdx.x; q < end; q += 4 * bd) {
        int q1 = q + bd, q2 = q + 2 * bd, q3 = q + 3 * bd;
        float4 va, vb, vc, vd;
        bool ga = true, gb = q1 < end, gc = q2 < end, gd = q3 < end;
        va = ((const float4*)scores)[q];
        if (gb) vb = ((const float4*)scores)[q1];
        if (gc) vc = ((const float4*)scores)[q2];
        if (gd) vd = ((const float4*)scores)[q3];
#define CPROC(g, qq, v4)                                                   \
        if (g) {                                                           \
            float vv[4] = {v4.x, v4.y, v4.z, v4.w};                        \
            _Pragma("unroll")                                              \
            for (int j = 0; j < 4; j++) {                                  \
                u32 e2 = ((u32)(qq) << 2) + (u32)j;                        \
                u32 r = (u32)(((u64)e2 * MAGIC11) >> 35);                  \
                u32 c = e2 - r * 11u;                                      \
                if (c != 0u) {                                             \
                    float s = __fmul_rn(vv[j], center[r]);                 \
                    if (s > SCORE_THR) {                                   \
                        u32 key = __float_as_uint(s);                      \
                        int b = (int)(key >> 14) - BASE14;                 \
                        b = min(max(b, 0), 4095);                          \
                        if ((u32)b >= thr) {                               \
                            u32 slot = atomicAdd(&binpos[b], 1u);          \
                            u32 pos = offs[b] + slot;                      \
                            if (pos < CAP) {                               \
                                u32 idx = r * 10u + (c - 1u);              \
                                buf[pos] = ((u64)key << 32) | (u64)(~idx); \
                            }                                              \
                        }                                                  \
                    }                                                      \
                }                                                          \
            }                                                              \
        }
        CPROC(ga, q, va) CPROC(gb, q1, vb) CPROC(gc, q2, vc) CPROC(gd, q3, vd)
#undef CPROC
    }
    if (blockIdx.x == 0 && threadIdx.x == 0) {       // tail (total_e % 4)
        for (int e2 = nq << 2; e2 < total_e; e2++) {
            u32 r = (u32)(((u64)(u32)e2 * MAGIC11) >> 35);
            u32 c = (u32)e2 - r * 11u;
            if (c != 0u) {
                float s = __fmul_rn(scores[e2], center[r]);
                if (s > SCORE_THR) {
                    u32 key = __float_as_uint(s);
                    int b = (int)(key >> 14) - BASE14;
                    b = min(max(b, 0), 4095);
                    if ((u32)b >= thr) {
                        u32 slot = atomicAdd(&binpos[b], 1u);
                        u32 pos = offs[b] + slot;
                        if (pos < CAP) {
                            u32 idx = r * 10u + (c - 1u);
                            buf[pos] = ((u64)key << 32) | (u64)(~idx);
                        }
                    }
                }
            }
        }
    }
}

// ---- per-ELEMENT rank (LDS-staged, O(run) per element) + scatter-write ----
__global__ __launch_bounds__(1024) void k_rank(
        const float* __restrict__ boxes, const u32* __restrict__ offs,
        const u32* __restrict__ hdr, const u64* __restrict__ buf,
        float* __restrict__ cand_bx, float* __restrict__ nms_bx,
        float* __restrict__ vals) {
    __shared__ u64 kb[CAP];
    __shared__ u32 lo[4096];
    int tid = threadIdx.x;
    u32 n = hdr[5]; if (n > (u32)CAP) n = CAP;
    u32 total = hdr[6];
    for (int t = tid; t < CAP; t += 1024) kb[t] = (t < (int)n) ? buf[t] : 0ull;
    for (int t = tid; t < 4096; t += 1024) lo[t] = offs[t];
    __syncthreads();
    for (int i = tid; i < (int)n; i += 1024) {
        u64 x = kb[i];
        u32 key = (u32)(x >> 32);
        int b = (int)(key >> 14) - BASE14;
        b = min(max(b, 0), 4095);
        u32 start = lo[b];
        u32 end = (b > 0) ? lo[b - 1] : total;
        if (end > (u32)CAP) end = CAP;
        u32 rk = start;                 // global rank = bin start + within-bin rank
        for (u32 j = start; j < end; j++) rk += (kb[j] > x) ? 1u : 0u;
        if (rk < (u32)TK) {
            u32 idx = ~(u32)x;
            u32 r = idx / 10u, cls = idx % 10u;
            const float* bp = boxes + (size_t)r * 4;
            float c0 = fminf(fmaxf(bp[0], 0.f), 1920.f);
            float c1 = fminf(fmaxf(bp[1], 0.f), 1080.f);
            float c2 = fminf(fmaxf(bp[2], 0.f), 1920.f);
            float c3 = fminf(fmaxf(bp[3], 0.f), 1080.f);
            float offv = __fmul_rn((float)cls, 3001.0f);  // exact: small ints
            cand_bx[rk * 4 + 0] = c0; cand_bx[rk * 4 + 1] = c1;
            cand_bx[rk * 4 + 2] = c2; cand_bx[rk * 4 + 3] = c3;
            nms_bx[rk * 4 + 0] = __fadd_rn(c0, offv);
            nms_bx[rk * 4 + 1] = __fadd_rn(c1, offv);
            nms_bx[rk * 4 + 2] = __fadd_rn(c2, offv);
            nms_bx[rk * 4 + 3] = __fadd_rn(c3, offv);
            vals[rk] = __uint_as_float(key);
        }
    }
}

// ---- suppression PAIRS (sparse): append (row<<11|col) for iou>thr, col>row ----
__global__ void k_mask(const float* __restrict__ nms_bx, u32* __restrict__ hdr,
                       u32* __restrict__ pairs) {
    int colbase = blockIdx.x * 64, rowbase = blockIdx.y * 64;
    if (colbase + 63 <= rowbase) return;   // whole tile has col <= row
    __shared__ float4 cb[64];
    __shared__ float ca[64];
    int tid = threadIdx.x;
    float4 c = ((const float4*)nms_bx)[colbase + tid];
    cb[tid] = c;
    ca[tid] = __fmul_rn(fmaxf(__fsub_rn(c.z, c.x), 0.f),
                        fmaxf(__fsub_rn(c.w, c.y), 0.f));
    int row = rowbase + tid;
    float4 rb = ((const float4*)nms_bx)[row];
    float rarea = __fmul_rn(fmaxf(__fsub_rn(rb.z, rb.x), 0.f),
                            fmaxf(__fsub_rn(rb.w, rb.y), 0.f));
    __syncthreads();
    for (int cc = 0; cc < 64; cc++) {
        int col = colbase + cc;
        if (col > row) {
            float4 cbv = cb[cc];
            float ltx = fmaxf(rb.x, cbv.x), lty = fmaxf(rb.y, cbv.y);
            float rbx = fminf(rb.z, cbv.z), rby = fminf(rb.w, cbv.w);
            float w = fmaxf(__fsub_rn(rbx, ltx), 0.f);
            float h = fmaxf(__fsub_rn(rby, lty), 0.f);
            float inter = __fmul_rn(w, h);
            // ref order: ((area_i + area_j) - inter) + 1e-9
            float denom = __fadd_rn(__fsub_rn(__fadd_rn(rarea, ca[cc]), inter), 1e-9f);
            float iou = __fdiv_rn(inter, denom);
            if (iou > NMS_THR) {
                u32 p = atomicAdd(&hdr[8], 1u);
                if (p < PAIR_CAP)
                    pairs[p] = ((u32)row << 11) | (u32)col;
            }
        }
    }
}

// ---- greedy scan over SPARSE pairs (one wave): counting-sort by row in LDS,
//      then exact serial greedy; keep = valid & ~removed (rows only suppressed
//      by earlier rows, so post-hoc evaluation is exact) ----
__global__ __launch_bounds__(64) void k_final(
        const u32* __restrict__ pairs, const u32* __restrict__ hdr,
        const float* __restrict__ vals, const float* __restrict__ cand_bx,
        float* __restrict__ out) {
    __shared__ u32 sp[PAIR_CAP];
    __shared__ u32 cur[2048];
    int lane = threadIdx.x;
    u32 np = hdr[8]; if (np > (u32)PAIR_CAP) np = PAIR_CAP;
    const float4* vp = (const float4*)vals + (size_t)lane * 8;
    float4 vv[8];
#pragma unroll
    for (int j = 0; j < 8; j++) vv[j] = vp[j];
    u32 validw = 0;
#pragma unroll
    for (int j = 0; j < 8; j++) {
        validw |= (vv[j].x > SCORE_THR ? 1u : 0u) << (4 * j + 0);
        validw |= (vv[j].y > SCORE_THR ? 1u : 0u) << (4 * j + 1);
        validw |= (vv[j].z > SCORE_THR ? 1u : 0u) << (4 * j + 2);
        validw |= (vv[j].w > SCORE_THR ? 1u : 0u) << (4 * j + 3);
    }
    for (int t = lane; t < 2048; t += 64) cur[t] = 0;
    __syncthreads();
    for (u32 k = lane; k < np; k += 64) atomicAdd(&cur[pairs[k] >> 11], 1u);
    __syncthreads();
    // ascending prefix sum: lane owns rows [32*lane, 32*lane+32)
    u32 cnt[32];
    u32 seg = 0;
#pragma unroll
    for (int j = 0; j < 32; j++) { cnt[j] = cur[lane * 32 + j]; seg += cnt[j]; }
    u32 incl = seg;
    for (int off = 1; off < 64; off <<= 1) {
        u32 t = (u32)__shfl_up((int)incl, off);
        if (lane >= off) incl += t;
    }
    u32 run = incl - seg;
#pragma unroll
    for (int j = 0; j < 32; j++) { cur[lane * 32 + j] = run; run += cnt[j]; }
    __syncthreads();
    for (u32 k = lane; k < np; k += 64) {
        u32 p = pairs[k];
        u32 pos = atomicAdd(&cur[p >> 11], 1u);
        sp[pos] = p;
    }
    __syncthreads();
    // exact greedy: pairs sorted by row ascending; cols always > row
    u32 removed = 0;
    for (u32 k = 0; k < np; k++) {
        u32 p = sp[k];
        u32 row = p >> 11, col = p & 2047u;
        u32 aw = (u32)__shfl((int)(validw & ~removed), (int)(row >> 5));
        if ((aw >> (row & 31)) & 1u)
            if (lane == (int)(col >> 5)) removed |= 1u << (col & 31);
    }
    u32 keepw = validw & ~removed;
#pragma unroll
    for (int b = 0; b < 32; b++) {
        int i = lane * 32 + b;
        bool kp = (keepw >> b) & 1u;
        const float4 bx = ((const float4*)cand_bx)[i];
        float v = (b & 3) == 0 ? vv[b >> 2].x :
                  (b & 3) == 1 ? vv[b >> 2].y :
                  (b & 3) == 2 ? vv[b >> 2].z : vv[b >> 2].w;
        out[i * 5 + 0] = kp ? bx.x : 0.f;
        out[i * 5 + 1] = kp ? bx.y : 0.f;
        out[i * 5 + 2] = kp ? bx.z : 0.f;
        out[i * 5 + 3] = kp ? bx.w : 0.f;
        out[i * 5 + 4] = kp ? v : 0.f;
    }
}

extern "C" void kernel_launch(void* const* d_in, const int* in_sizes, int n_in,
                              void* d_out, int out_size, void* d_ws, size_t ws_size,
                              hipStream_t stream) {
    const float* boxes = (const float*)d_in[0];
    const float* scores = (const float*)d_in[1];
    const float* center = (const float*)d_in[2];
    float* out = (float*)d_out;
    int R = in_sizes[2];

    char* w = (char*)d_ws;
    u32* offs   = (u32*)(w + WS_OFFS);
    u32* binpos = (u32*)(w + WS_BINPOS);
    u32* hdr    = (u32*)(w + WS_HDR);
    float* cbx  = (float*)(w + WS_CBX);
    float* nbx  = (float*)(w + WS_NBX);
    float* vls  = (float*)(w + WS_VALS);
    u32* hrep   = (u32*)(w + WS_HREP);
    u64* buf    = (u64*)(w + WS_BUF);
    u32* pairs  = (u32*)(w + WS_PAIRS);

    // zero binpos+hdr+cand/nms/vals padding+hrep (offs fully written by k_scan;
    // buf fully written by k_collect; pairs clamped by hdr[8])
    hipMemsetAsync(w + WS_BINPOS, 0, WS_BUF - WS_BINPOS, stream);

    k_hist<<<SGRID, 256, 0, stream>>>(scores, center, R, hrep);
    k_scan<<<1, 64, 0, stream>>>(hrep, offs, hdr);
    k_collect<<<SGRID, 256, 0, stream>>>(scores, center, R, hdr, offs, binpos, buf);
    k_rank<<<1, 1024, 0, stream>>>(boxes, offs, hdr, buf, cbx, nbx, vls);
    k_mask<<<dim3(32, 32), 64, 0, stream>>>(nbx, hdr, pairs);
    k_final<<<1, 64, 0, stream>>>(pairs, hdr, vls, cbx, out);
}